// Round 9
// baseline (86.552 us; speedup 1.0000x reference)
//
#include <hip/hip_runtime.h>
#include <hip/hip_bf16.h>

// Problem: B=4, S=128, H=768, OUT*TAG=96
// scores[b,i,j,o] = sum_k relu(head[b,i,k] + tail[b,j,k] + b1[k]) * W2[k,o] + b2[o]
// R8: k_pair = q=4 i-rows/wave (each W2 LDS read feeds 4 MFMAs), 256 blocks x 4 waves,
//     K-step 64, 3-buffer LDS ring (36KB), stage-after-barrier, counted vmcnt(23).

typedef __bf16 bf16x8 __attribute__((ext_vector_type(8)));
typedef float f32x4 __attribute__((ext_vector_type(4)));

#define S_   128
#define H_   768
#define K3   2304   // 3*H
#define NOUT 96
#define NIT  36     // K-step-64 iterations

__device__ __forceinline__ unsigned short f2bf(float f) {
    union { __bf16 b; unsigned short u; } c;
    c.b = (__bf16)f;   // RNE
    return c.u;
}

__device__ __forceinline__ void gload_lds16(const unsigned short* g, unsigned short* l) {
    __builtin_amdgcn_global_load_lds(
        (const __attribute__((address_space(1))) void*)g,
        (__attribute__((address_space(3))) void*)l,
        16, 0, 0);
}

// ---------- prep: x fp32 -> bf16 (layout unchanged, [512][768]) ----------
__global__ void k_cvt_x(const float4* __restrict__ x, ushort4* __restrict__ xb) {
    int t = blockIdx.x * 256 + threadIdx.x;   // 98304 threads, exact
    float4 v = x[t];
    ushort4 o;
    o.x = f2bf(v.x); o.y = f2bf(v.y); o.z = f2bf(v.z); o.w = f2bf(v.w);
    xb[t] = o;
}

// ---------- prep: transpose fp32 [R][C] -> bf16 [C][R] (dims multiple of 32) ----------
__global__ void k_transpose(const float* __restrict__ src, unsigned short* __restrict__ dst,
                            int R, int C, long srcZ, long dstZ) {
    src += (long)blockIdx.z * srcZ;
    dst += (long)blockIdx.z * dstZ;
    __shared__ float tile[32][33];
    int c0 = blockIdx.x * 32, r0 = blockIdx.y * 32;
    int row = threadIdx.x >> 3;          // 0..31
    int c4  = (threadIdx.x & 7) * 4;     // 0..28
    float4 v = *(const float4*)(src + (size_t)(r0 + row) * C + c0 + c4);
    tile[row][c4 + 0] = v.x; tile[row][c4 + 1] = v.y;
    tile[row][c4 + 2] = v.z; tile[row][c4 + 3] = v.w;
    __syncthreads();
    ushort4 o;
    o.x = f2bf(tile[c4 + 0][row]); o.y = f2bf(tile[c4 + 1][row]);
    o.z = f2bf(tile[c4 + 2][row]); o.w = f2bf(tile[c4 + 3][row]);
    *(ushort4*)(dst + (size_t)(c0 + row) * R + r0 + c4) = o;
}

// ---------- prep: pack W2T bf16 [96][2304] into fragment order [72][6][64][8] ----------
// frag elem(kc,f,l,e) = W2T[f*16 + (l&15)][kc*32 + (l>>4)*8 + e]
__global__ void k_pack_w2(const unsigned short* __restrict__ w2t,
                          unsigned short* __restrict__ w2f) {
    int t = blockIdx.x * 256 + threadIdx.x;   // 27648 threads exact (108 blocks)
    int l = t & 63, f = (t >> 6) % 6, kc = t / 384;
    const unsigned short* src = w2t + (size_t)(f * 16 + (l & 15)) * K3 + kc * 32 + (l >> 4) * 8;
    *(uint4*)(w2f + (size_t)t * 8) = *(const uint4*)src;   // 16B per lane slot
}

// ---------- GEMM1 (R1-verbatim): head -> headb, tail+b1 -> tailb, both row-major ----------
__global__ __launch_bounds__(256) void k_gemm1(
        const unsigned short* __restrict__ xb,     // [512][768] bf16
        const unsigned short* __restrict__ w1t,    // [4608][768] bf16
        const float* __restrict__ b1,              // [2304]
        unsigned short* __restrict__ headb,        // [512][2304] bf16
        unsigned short* __restrict__ tailb) {      // [512][2304] bf16
    __shared__ unsigned short As[128 * 32];
    __shared__ unsigned short Bs[128 * 32];
    const int tid = threadIdx.x;
    const int l = tid & 63, w = tid >> 6;
    const int m0 = blockIdx.y * 128;
    const int n0 = blockIdx.x * 128;
    const int wr = (w >> 1) * 64, wc = (w & 1) * 64;
    const int lr = l & 15, lk = (l >> 4) * 8;
    f32x4 acc[4][4] = {};

    for (int kt = 0; kt < H_; kt += 32) {
#pragma unroll
        for (int p = 0; p < 2; ++p) {
            int idx = p * 256 + tid;
            int row = idx >> 2, seg = (idx & 3) * 8;
            gload_lds16(xb  + (size_t)(m0 + row) * H_ + kt + seg, As + idx * 8);
            gload_lds16(w1t + (size_t)(n0 + row) * H_ + kt + seg, Bs + idx * 8);
        }
        asm volatile("s_waitcnt vmcnt(0)" ::: "memory");
        __syncthreads();
        bf16x8 af[4], bfr[4];
#pragma unroll
        for (int i = 0; i < 4; i++) af[i]  = *(const bf16x8*)(As + (wr + i * 16 + lr) * 32 + lk);
#pragma unroll
        for (int j = 0; j < 4; j++) bfr[j] = *(const bf16x8*)(Bs + (wc + j * 16 + lr) * 32 + lk);
#pragma unroll
        for (int i = 0; i < 4; i++)
#pragma unroll
            for (int j = 0; j < 4; j++)
                acc[i][j] = __builtin_amdgcn_mfma_f32_16x16x32_bf16(af[i], bfr[j], acc[i][j], 0, 0, 0);
        __syncthreads();
    }

    const bool tailblk = (n0 >= K3);
    unsigned short* dst = tailblk ? tailb : headb;
    const int nloc = n0 - (tailblk ? K3 : 0);
    const int lv = (l >> 4) * 4;
#pragma unroll
    for (int j = 0; j < 4; j++) {
        int c = nloc + wc + j * 16 + lr;
        float bias = tailblk ? b1[c] : 0.0f;
#pragma unroll
        for (int i = 0; i < 4; i++) {
            int mrow = m0 + wr + i * 16 + lv;
#pragma unroll
            for (int e = 0; e < 4; e++)
                dst[(size_t)(mrow + e) * K3 + c] = f2bf(acc[i][j][e] + bias);
        }
    }
}

// ---------- main pair kernel ----------
// 256 thr (4 waves), block tile 16i x 16j; wave w owns i = i0+4w .. i0+4w+3 (q=4).
// W2 frags: 3-deep LDS ring (3 x 12KB), staged 2 iters ahead via global_load_lds
// right after the barrier; counted vmcnt(23) — never drain to 0.
// Safety (3-buf ring): stage(n+2) clobbers buf (n-1)%3; every wave's iter-(n-1)
// ds_reads are lgkm-drained before its MFMA(n-1), which precedes barrier(n),
// which precedes any wave's stage(n+2) issue.
__device__ __forceinline__ void expand8(uint4 t, float* o) {
    union { uint4 q; unsigned short s[8]; } T; T.q = t;
#pragma unroll
    for (int e = 0; e < 8; e++) o[e] = __uint_as_float((unsigned)T.s[e] << 16);
}

__device__ __forceinline__ bf16x8 form8t(uint4 h, const float* tf) {
    union { uint4 q; unsigned short s[8]; } H; H.q = h;
    bf16x8 r;
#pragma unroll
    for (int e = 0; e < 8; e++) {
        float hv = __uint_as_float((unsigned)H.s[e] << 16);
        r[e] = (__bf16)fmaxf(hv + tf[e], 0.0f);
    }
    return r;
}

__global__ __launch_bounds__(256, 1) void k_pair(
        const unsigned short* __restrict__ headb,  // [512][2304] bf16
        const unsigned short* __restrict__ tailb,  // [512][2304] bf16
        const unsigned short* __restrict__ w2f,    // [72][6][64][8] bf16 frag order
        const float* __restrict__ b2,              // [96]
        float* __restrict__ out) {                 // [4][128][128][96] fp32
    // 3-deep ring of K-step-64 W2 buffers: 3 x 12KB = 36KB
    __shared__ __align__(16) unsigned short lds[3][6144];

    const int tid = threadIdx.x;
    const int w = tid >> 6, l = tid & 63;
    const int lr = l & 15, lkq = l >> 4;
    const int lkoff = lkq * 8;
    const int jb = blockIdx.x;     // 0..7
    const int ig = blockIdx.y;     // 0..7
    const int b  = blockIdx.z;     // 0..3
    const int i0 = ig * 16 + w * 4;

    const unsigned short* Hp = headb + (size_t)(b * S_ + i0) * K3;           // 4 rows
    const unsigned short* Tp = tailb + (size_t)(b * S_ + jb * 16 + lr) * K3; // per-lane j row

    f32x4 acc[4][6] = {};
    float b2v[6];
#pragma unroll
    for (int f = 0; f < 6; f++) b2v[f] = b2[f * 16 + lr];

    // stage K-step n (12KB) into ring buffer sbuf: 3 x 16B/thread
    auto stage = [&](int sbuf, int n) {
        const unsigned short* src = w2f + (size_t)n * 6144;
        unsigned short* dst = &lds[sbuf][0];
#pragma unroll
        for (int i = 0; i < 3; ++i)
            gload_lds16(src + i * 2048 + tid * 8, dst + i * 2048 + tid * 8);
    };

    stage(0, 0);
    stage(1, 1);

    // h/t registers for iter 0 (2 chunks x (1 tail + 4 head) = 10 loads)
    uint4 t8[2], h8[4][2];
#pragma unroll
    for (int kk = 0; kk < 2; kk++) {
        t8[kk] = *(const uint4*)(Tp + kk * 32 + lkoff);
#pragma unroll
        for (int q = 0; q < 4; q++)
            h8[q][kk] = *(const uint4*)(Hp + q * K3 + kk * 32 + lkoff);
    }

    for (int n = 0; n < NIT; ++n) {
        // depth-1 h/t register prefetch (10 loads; clamped on last iter)
        const int kn = ((n < NIT - 1) ? (n + 1) : n) * 64;
        uint4 t8n[2], h8n[4][2];
#pragma unroll
        for (int kk = 0; kk < 2; kk++) {
            t8n[kk] = *(const uint4*)(Tp + kn + kk * 32 + lkoff);
#pragma unroll
            for (int q = 0; q < 4; q++)
                h8n[q][kk] = *(const uint4*)(Hp + q * K3 + kn + kk * 32 + lkoff);
        }

        // counted wait: younger-than-stage(n) = ht(n)[10] + stage(n+1)[3] + ht(n+1)[10] = 23.
        // Forces stage(n) landed; keeps stage(n+1) and both ht prefetches in flight.
        asm volatile("s_waitcnt vmcnt(23)" ::: "memory");
        __builtin_amdgcn_s_barrier();

        // stage n+2 (dummy clamped re-stage of last chunk keeps vmcnt counts uniform;
        // it writes buf (n+2)%3 whose readers finished before the barrier above)
        stage((n + 2) % 3, (n + 2 < NIT) ? (n + 2) : (NIT - 1));

        const unsigned short* Lb = &lds[n % 3][0];
#pragma unroll
        for (int kk = 0; kk < 2; kk++) {
            float tf[8];
            expand8(t8[kk], tf);
            bf16x8 a[4];
#pragma unroll
            for (int q = 0; q < 4; q++) a[q] = form8t(h8[q][kk], tf);
#pragma unroll
            for (int f = 0; f < 6; f++) {
                bf16x8 bfr = *(const bf16x8*)(Lb + kk * 3072 + f * 512 + l * 8);
#pragma unroll
                for (int q = 0; q < 4; q++)
                    acc[q][f] = __builtin_amdgcn_mfma_f32_16x16x32_bf16(a[q], bfr, acc[q][f], 0, 0, 0);
            }
        }
#pragma unroll
        for (int kk = 0; kk < 2; kk++) {
            t8[kk] = t8n[kk];
#pragma unroll
            for (int q = 0; q < 4; q++) h8[q][kk] = h8n[q][kk];
        }
    }

    float* O = out + (((size_t)(b * S_ + i0)) * S_ + jb * 16) * NOUT;
#pragma unroll
    for (int q = 0; q < 4; q++)
#pragma unroll
        for (int f = 0; f < 6; f++)
#pragma unroll
            for (int e = 0; e < 4; e++) {
                int j = lkq * 4 + e;
                O[(size_t)q * S_ * NOUT + (size_t)j * NOUT + f * 16 + lr] = acc[q][f][e] + b2v[f];
            }
}

extern "C" void kernel_launch(void* const* d_in, const int* in_sizes, int n_in,
                              void* d_out, int out_size, void* d_ws, size_t ws_size,
                              hipStream_t stream) {
    const float* x  = (const float*)d_in[0];   // [4][128][768]
    const float* W1 = (const float*)d_in[1];   // [1536][2304]
    const float* b1 = (const float*)d_in[2];   // [2304]
    const float* W2 = (const float*)d_in[3];   // [2304][96]
    const float* b2 = (const float*)d_in[4];   // [96]
    float* out = (float*)d_out;

    char* ws = (char*)d_ws;
    unsigned short* xb    = (unsigned short*)(ws);              //  512*768   bf16
    unsigned short* w2f   = (unsigned short*)(ws);              //  72*6*64*8 bf16 (overlays xb; written after gemm1)
    unsigned short* w1t   = (unsigned short*)(ws +   786432);   // 4608*768   bf16
    unsigned short* w2t   = (unsigned short*)(ws +  7864320);   //   96*2304  bf16
    unsigned short* headb = (unsigned short*)(ws +  8306688);   //  512*2304  bf16
    unsigned short* tailb = (unsigned short*)(ws + 10665984);   //  512*2304  bf16
    // total ws use: 13,025,280 bytes

    hipLaunchKernelGGL(k_cvt_x, dim3(384), dim3(256), 0, stream,
                       (const float4*)x, (ushort4*)xb);
    hipLaunchKernelGGL(k_transpose, dim3(72, 24, 2), dim3(256), 0, stream,
                       W1, w1t, H_, K3, (long)H_ * K3, (long)K3 * H_);
    hipLaunchKernelGGL(k_transpose, dim3(3, 72, 1), dim3(256), 0, stream,
                       W2, w2t, K3, NOUT, 0L, 0L);
    hipLaunchKernelGGL(k_gemm1, dim3(36, 4), dim3(256), 0, stream,
                       xb, w1t, b1, headb, tailb);
    // pack W2 frags AFTER gemm1 (w2f overlays xb, which gemm1 reads)
    hipLaunchKernelGGL(k_pack_w2, dim3(108), dim3(256), 0, stream,
                       w2t, w2f);
    hipLaunchKernelGGL(k_pair, dim3(8, 8, 4), dim3(256), 0, stream,
                       headb, tailb, w2f, b2, out);
}

// Round 11
// 74.980 us; speedup vs baseline: 1.1543x; 1.1543x over previous
//
#include <hip/hip_runtime.h>
#include <hip/hip_bf16.h>

// Problem: B=4, S=128, H=768, OUT*TAG=96
// scores[b,i,j,o] = sum_k relu(head[b,i,k] + tail[b,j,k] + b1[k]) * W2[k,o] + b2[o]
// R10: R9 (f16 pair-GEMM operand path) with the compile fix: packed f16 form via
//      native vector ops + __builtin_elementwise_max (v_pk_add_f16 / v_pk_max_f16),
//      avoiding the __hmax2 bf16/f16 overload ambiguity.

typedef __bf16 bf16x8 __attribute__((ext_vector_type(8)));
typedef _Float16 f16x8 __attribute__((ext_vector_type(8)));
typedef float f32x4 __attribute__((ext_vector_type(4)));

#define S_   128
#define H_   768
#define K3   2304   // 3*H
#define NOUT 96
#define NIT  36     // K-step-64 iterations (72 chunks / 2)

__device__ __forceinline__ unsigned short f2bf(float f) {
    union { __bf16 b; unsigned short u; } c;
    c.b = (__bf16)f;   // RNE
    return c.u;
}

__device__ __forceinline__ unsigned short f2h(float f) {
    union { _Float16 h; unsigned short u; } c;
    c.h = (_Float16)f;
    return c.u;
}

__device__ __forceinline__ void gload_lds16(const unsigned short* g, unsigned short* l) {
    __builtin_amdgcn_global_load_lds(
        (const __attribute__((address_space(1))) void*)g,
        (__attribute__((address_space(3))) void*)l,
        16, 0, 0);
}

// ---------- prep: x fp32 -> bf16 (layout unchanged, [512][768]) ----------
__global__ void k_cvt_x(const float4* __restrict__ x, ushort4* __restrict__ xb) {
    int t = blockIdx.x * 256 + threadIdx.x;   // 98304 threads, exact
    float4 v = x[t];
    ushort4 o;
    o.x = f2bf(v.x); o.y = f2bf(v.y); o.z = f2bf(v.z); o.w = f2bf(v.w);
    xb[t] = o;
}

// ---------- prep: transpose fp32 [R][C] -> bf16 [C][R] (for W1) ----------
__global__ void k_transpose(const float* __restrict__ src, unsigned short* __restrict__ dst,
                            int R, int C, long srcZ, long dstZ) {
    src += (long)blockIdx.z * srcZ;
    dst += (long)blockIdx.z * dstZ;
    __shared__ float tile[32][33];
    int c0 = blockIdx.x * 32, r0 = blockIdx.y * 32;
    int row = threadIdx.x >> 3;          // 0..31
    int c4  = (threadIdx.x & 7) * 4;     // 0..28
    float4 v = *(const float4*)(src + (size_t)(r0 + row) * C + c0 + c4);
    tile[row][c4 + 0] = v.x; tile[row][c4 + 1] = v.y;
    tile[row][c4 + 2] = v.z; tile[row][c4 + 3] = v.w;
    __syncthreads();
    ushort4 o;
    o.x = f2bf(tile[c4 + 0][row]); o.y = f2bf(tile[c4 + 1][row]);
    o.z = f2bf(tile[c4 + 2][row]); o.w = f2bf(tile[c4 + 3][row]);
    *(ushort4*)(dst + (size_t)(c0 + row) * R + r0 + c4) = o;
}

// ---------- prep: pack W2 f32 [2304][96] -> f16 fragment order [72][6][64][8] ----------
// frag elem(kc,f,l,e) = W2[kc*32 + (l>>4)*8 + e][f*16 + (l&15)]  as f16
__global__ void k_pack_w2(const float* __restrict__ W2,
                          unsigned short* __restrict__ w2f) {
    int t = blockIdx.x * 256 + threadIdx.x;   // 27648 threads exact (108 blocks)
    int l = t & 63, f = (t >> 6) % 6, kc = t / 384;
    int k0 = kc * 32 + (l >> 4) * 8;
    int o  = f * 16 + (l & 15);
    unsigned short v[8];
#pragma unroll
    for (int e = 0; e < 8; e++)
        v[e] = f2h(W2[(size_t)(k0 + e) * NOUT + o]);
    *(uint4*)(w2f + (size_t)t * 8) = *(const uint4*)v;
}

// ---------- GEMM1: bf16 MFMA, outputs stored as f16 ----------
__global__ __launch_bounds__(256) void k_gemm1(
        const unsigned short* __restrict__ xb,     // [512][768] bf16
        const unsigned short* __restrict__ w1t,    // [4608][768] bf16
        const float* __restrict__ b1,              // [2304]
        unsigned short* __restrict__ headh,        // [512][2304] f16
        unsigned short* __restrict__ tailh) {      // [512][2304] f16
    __shared__ unsigned short As[128 * 32];
    __shared__ unsigned short Bs[128 * 32];
    const int tid = threadIdx.x;
    const int l = tid & 63, w = tid >> 6;
    const int m0 = blockIdx.y * 128;
    const int n0 = blockIdx.x * 128;
    const int wr = (w >> 1) * 64, wc = (w & 1) * 64;
    const int lr = l & 15, lk = (l >> 4) * 8;
    f32x4 acc[4][4] = {};

    for (int kt = 0; kt < H_; kt += 32) {
#pragma unroll
        for (int p = 0; p < 2; ++p) {
            int idx = p * 256 + tid;
            int row = idx >> 2, seg = (idx & 3) * 8;
            gload_lds16(xb  + (size_t)(m0 + row) * H_ + kt + seg, As + idx * 8);
            gload_lds16(w1t + (size_t)(n0 + row) * H_ + kt + seg, Bs + idx * 8);
        }
        asm volatile("s_waitcnt vmcnt(0)" ::: "memory");
        __syncthreads();
        bf16x8 af[4], bfr[4];
#pragma unroll
        for (int i = 0; i < 4; i++) af[i]  = *(const bf16x8*)(As + (wr + i * 16 + lr) * 32 + lk);
#pragma unroll
        for (int j = 0; j < 4; j++) bfr[j] = *(const bf16x8*)(Bs + (wc + j * 16 + lr) * 32 + lk);
#pragma unroll
        for (int i = 0; i < 4; i++)
#pragma unroll
            for (int j = 0; j < 4; j++)
                acc[i][j] = __builtin_amdgcn_mfma_f32_16x16x32_bf16(af[i], bfr[j], acc[i][j], 0, 0, 0);
        __syncthreads();
    }

    const bool tailblk = (n0 >= K3);
    unsigned short* dst = tailblk ? tailh : headh;
    const int nloc = n0 - (tailblk ? K3 : 0);
    const int lv = (l >> 4) * 4;
#pragma unroll
    for (int j = 0; j < 4; j++) {
        int c = nloc + wc + j * 16 + lr;
        float bias = tailblk ? b1[c] : 0.0f;
#pragma unroll
        for (int i = 0; i < 4; i++) {
            int mrow = m0 + wr + i * 16 + lv;
#pragma unroll
            for (int e = 0; e < 4; e++)
                dst[(size_t)(mrow + e) * K3 + c] = f2h(acc[i][j][e] + bias);
        }
    }
}

// ---------- main pair kernel (f16) ----------
// 256 thr (4 waves), tile 8i x 16j; wave w owns i = i0+2w, i0+2w+1.
// W2 frags: 4-deep LDS ring (4 x 12KB), staged depth-2 via global_load_lds,
// one raw s_barrier per K-step-64 iter, counted vmcnt(9).
// Form: v_pk_add_f16 + v_pk_max_f16 (1 VALU per elem) via native vector ops.
__device__ __forceinline__ f16x8 form8h(uint4 hq, uint4 tq) {
    union { uint4 q; f16x8 v; } H, T;
    H.q = hq; T.q = tq;
    f16x8 s = H.v + T.v;
    const f16x8 z = {0, 0, 0, 0, 0, 0, 0, 0};
    return __builtin_elementwise_max(s, z);
}

__global__ __launch_bounds__(256) void k_pair(
        const unsigned short* __restrict__ headh,  // [512][2304] f16
        const unsigned short* __restrict__ tailh,  // [512][2304] f16
        const unsigned short* __restrict__ w2f,    // [72][6][64][8] f16 frag order
        const float* __restrict__ b2,              // [96]
        float* __restrict__ out) {                 // [4][128][128][96] fp32
    // 4-deep ring of K-step-64 W2 buffers: 4 x 12KB = 48KB
    __shared__ __align__(16) unsigned short lds[4][6144];

    const int tid = threadIdx.x;
    const int w = tid >> 6, l = tid & 63;
    const int lr = l & 15, lkq = l >> 4;
    const int lkoff = lkq * 8;
    const int jb = blockIdx.x;     // 0..7
    const int ig = blockIdx.y;     // 0..15
    const int b  = blockIdx.z;     // 0..3
    const int i0 = ig * 8;

    const unsigned short* Hp = headh + (size_t)(b * S_ + i0 + 2 * w) * K3;
    const unsigned short* Tp = tailh + (size_t)(b * S_ + jb * 16 + lr) * K3;

    f32x4 acc[2][6] = {};
    float b2v[6];
#pragma unroll
    for (int f = 0; f < 6; f++) b2v[f] = b2[f * 16 + lr];

    // stage K-step n (12KB = chunks 2n, 2n+1) into ring buffer sbuf: 3 x 16B/thread
    auto stage = [&](int sbuf, int n) {
        const unsigned short* src = w2f + (size_t)n * 6144;
#pragma unroll
        for (int i = 0; i < 3; ++i)
            gload_lds16(src + i * 2048 + tid * 8, &lds[sbuf][i * 2048 + tid * 8]);
    };

    // current h/t registers (for iter 0)
    uint4 t8[2], ha[2], hb[2];
#pragma unroll
    for (int kk = 0; kk < 2; kk++) {
        t8[kk] = *(const uint4*)(Tp + kk * 32 + lkoff);
        ha[kk] = *(const uint4*)(Hp + kk * 32 + lkoff);
        hb[kk] = *(const uint4*)(Hp + K3 + kk * 32 + lkoff);
    }

    stage(0, 0);
    stage(1, 1);

    for (int n = 0; n < NIT; ++n) {
        // depth-2 W2 staging
        if (n + 2 < NIT) stage((n + 2) & 3, n + 2);
        // depth-1 h/t register prefetch (6 vector loads)
        const int kn = ((n < NIT - 1) ? (n + 1) : n) * 64;
        uint4 t8n[2], han[2], hbn[2];
#pragma unroll
        for (int kk = 0; kk < 2; kk++) {
            t8n[kk] = *(const uint4*)(Tp + kn + kk * 32 + lkoff);
            han[kk] = *(const uint4*)(Hp + kn + kk * 32 + lkoff);
            hbn[kk] = *(const uint4*)(Hp + K3 + kn + kk * 32 + lkoff);
        }

        // counted wait: keep stage(n+2) [3] and ht(n+1) [6] in flight;
        // guarantees stage(n) (issued 2 iters ago, >=9 ops older) has landed.
        asm volatile("s_waitcnt vmcnt(9)" ::: "memory");
        __builtin_amdgcn_s_barrier();

        const unsigned short* Lb = &lds[n & 3][0];
#pragma unroll
        for (int kk = 0; kk < 2; kk++) {
            f16x8 a0 = form8h(ha[kk], t8[kk]);
            f16x8 a1 = form8h(hb[kk], t8[kk]);
#pragma unroll
            for (int f = 0; f < 6; f++) {
                f16x8 bfr = *(const f16x8*)(Lb + kk * 3072 + f * 512 + l * 8);
                acc[0][f] = __builtin_amdgcn_mfma_f32_16x16x32_f16(a0, bfr, acc[0][f], 0, 0, 0);
                acc[1][f] = __builtin_amdgcn_mfma_f32_16x16x32_f16(a1, bfr, acc[1][f], 0, 0, 0);
            }
        }
#pragma unroll
        for (int kk = 0; kk < 2; kk++) { t8[kk] = t8n[kk]; ha[kk] = han[kk]; hb[kk] = hbn[kk]; }
    }

    float* O = out + (((size_t)(b * S_ + i0 + 2 * w)) * S_ + jb * 16) * NOUT;
#pragma unroll
    for (int q = 0; q < 2; q++)
#pragma unroll
        for (int f = 0; f < 6; f++)
#pragma unroll
            for (int e = 0; e < 4; e++) {
                int j = lkq * 4 + e;
                O[(size_t)q * S_ * NOUT + (size_t)j * NOUT + f * 16 + lr] = acc[q][f][e] + b2v[f];
            }
}

extern "C" void kernel_launch(void* const* d_in, const int* in_sizes, int n_in,
                              void* d_out, int out_size, void* d_ws, size_t ws_size,
                              hipStream_t stream) {
    const float* x  = (const float*)d_in[0];   // [4][128][768]
    const float* W1 = (const float*)d_in[1];   // [1536][2304]
    const float* b1 = (const float*)d_in[2];   // [2304]
    const float* W2 = (const float*)d_in[3];   // [2304][96]
    const float* b2 = (const float*)d_in[4];   // [96]
    float* out = (float*)d_out;

    char* ws = (char*)d_ws;
    unsigned short* xb    = (unsigned short*)(ws);              //  512*768   bf16
    unsigned short* w2f   = (unsigned short*)(ws);              //  72*6*64*8 f16 (overlays xb; written after gemm1)
    unsigned short* w1t   = (unsigned short*)(ws +   786432);   // 4608*768   bf16
    unsigned short* headh = (unsigned short*)(ws +  8306688);   //  512*2304  f16
    unsigned short* tailh = (unsigned short*)(ws + 10665984);   //  512*2304  f16
    // total ws use: 13,025,280 bytes

    hipLaunchKernelGGL(k_cvt_x, dim3(384), dim3(256), 0, stream,
                       (const float4*)x, (ushort4*)xb);
    hipLaunchKernelGGL(k_transpose, dim3(72, 24, 2), dim3(256), 0, stream,
                       W1, w1t, H_, K3, (long)H_ * K3, (long)K3 * H_);
    hipLaunchKernelGGL(k_gemm1, dim3(36, 4), dim3(256), 0, stream,
                       xb, w1t, b1, headh, tailh);
    // pack W2 frags AFTER gemm1 (w2f overlays xb, which gemm1 reads)
    hipLaunchKernelGGL(k_pack_w2, dim3(108), dim3(256), 0, stream,
                       W2, w2f);
    hipLaunchKernelGGL(k_pair, dim3(8, 16, 4), dim3(256), 0, stream,
                       headh, tailh, w2f, b2, out);
}